// Round 6
// baseline (475.165 us; speedup 1.0000x reference)
//
#include <hip/hip_runtime.h>
#include <hip/hip_bf16.h>

// TimeFeatureEmbedding: y[b,t,d] = sum_e x[b,t,e]*W[d,e] + b[d], broadcast to
// [B,T,S,D]. D=512, d_inp=4, S=64. 402.7 MB fp32 stores -> write-BW-bound.
//
// R5 post-mortem: nt stores regressed (L3 write-combining was helping);
// R3's pure-store phase was confounded by 2-blocks/CU occupancy. Remaining
// theory: R2's rolled loop serializes store(i) -> load(i+1) -> waitcnt
// vmcnt(0), so each wave pays full store-ack latency per 1KB store (loads
// and stores share the in-order vmcnt counter). Fix: bt is BLOCK-uniform,
// so derive the x address from blockIdx.x only -> compiler emits
// s_load_dwordx4 (scalar cache, lgkmcnt) -> the loop contains ZERO vmem
// loads; stores are fire-and-forget like the 6.3 TB/s fill kernel, at full
// 8-blocks/CU occupancy (VGPR ~40, capped by launch_bounds(256,8)).

#define D_MODEL 512
#define D_INP   4

template<int ITERS>
__global__ __launch_bounds__(256, 8) void tfe_sload(
    const float4* __restrict__ x4,   // [BT]  x rows as float4
    const float4* __restrict__ W4,   // [512] each W row is one float4
    const float4* __restrict__ b4,   // [128] bias as float4
    float4* __restrict__ out4)       // flat output as float4
{
    // Specialized: S=64 -> bt-chunk = S*128 = 8192 float4; stride = 2048*256
    // = 524288 float4 -> btStep = 64. Block spans 4KB < chunk, so bt is
    // block-uniform: bt0 = (blockIdx.x*256) >> 13 = blockIdx.x >> 5.
    const int bt0 = (int)(blockIdx.x >> 5);          // SGPR-only -> uniform
    const size_t stride = (size_t)gridDim.x * 256;   // 524288
    const size_t f0 = (size_t)blockIdx.x * 256 + threadIdx.x;
    const int d4 = (int)(f0 & 127);

    const float4 w0 = W4[4 * d4 + 0];
    const float4 w1 = W4[4 * d4 + 1];
    const float4 w2 = W4[4 * d4 + 2];
    const float4 w3 = W4[4 * d4 + 3];
    const float4 bv = b4[d4];

    size_t f = f0;
#pragma unroll
    for (int i = 0; i < ITERS; ++i, f += stride) {
        // Uniform address (pure blockIdx/i arithmetic) -> s_load_dwordx4,
        // scalar cache, lgkmcnt — does NOT touch vmcnt.
        const float4 xv = x4[bt0 + i * 64];
        float4 y;
        y.x = fmaf(xv.x, w0.x, fmaf(xv.y, w0.y, fmaf(xv.z, w0.z, fmaf(xv.w, w0.w, bv.x))));
        y.y = fmaf(xv.x, w1.x, fmaf(xv.y, w1.y, fmaf(xv.z, w1.z, fmaf(xv.w, w1.w, bv.y))));
        y.z = fmaf(xv.x, w2.x, fmaf(xv.y, w2.y, fmaf(xv.z, w2.z, fmaf(xv.w, w2.w, bv.z))));
        y.w = fmaf(xv.x, w3.x, fmaf(xv.y, w3.y, fmaf(xv.z, w3.z, fmaf(xv.w, w3.w, bv.w))));
        out4[f] = y;   // fire-and-forget: no vmem load ever waits on it
    }
}

// Generic fallback (any S / sizes): flat grid-stride with in-loop load.
__global__ __launch_bounds__(256) void tfe_flat(
    const float4* __restrict__ x4, const float4* __restrict__ W4,
    const float4* __restrict__ b4, float4* __restrict__ out4,
    size_t N4, int rowLen /* S*128 */)
{
    const size_t stride = (size_t)gridDim.x * blockDim.x;
    for (size_t f = (size_t)blockIdx.x * blockDim.x + threadIdx.x; f < N4; f += stride) {
        const int d4 = (int)(f & 127);
        const int bt = (int)(f / (size_t)rowLen);
        const float4 xv = x4[bt];
        const float4 w0 = W4[4 * d4 + 0];
        const float4 w1 = W4[4 * d4 + 1];
        const float4 w2 = W4[4 * d4 + 2];
        const float4 w3 = W4[4 * d4 + 3];
        const float4 bv = b4[d4];
        float4 y;
        y.x = fmaf(xv.x, w0.x, fmaf(xv.y, w0.y, fmaf(xv.z, w0.z, fmaf(xv.w, w0.w, bv.x))));
        y.y = fmaf(xv.x, w1.x, fmaf(xv.y, w1.y, fmaf(xv.z, w1.z, fmaf(xv.w, w1.w, bv.y))));
        y.z = fmaf(xv.x, w2.x, fmaf(xv.y, w2.y, fmaf(xv.z, w2.z, fmaf(xv.w, w2.w, bv.z))));
        y.w = fmaf(xv.x, w3.x, fmaf(xv.y, w3.y, fmaf(xv.z, w3.z, fmaf(xv.w, w3.w, bv.w))));
        out4[f] = y;
    }
}

extern "C" void kernel_launch(void* const* d_in, const int* in_sizes, int n_in,
                              void* d_out, int out_size, void* d_ws, size_t ws_size,
                              hipStream_t stream) {
    const float* x    = (const float*)d_in[0];   // [B,T,4] fp32
    const float* W    = (const float*)d_in[2];   // [512,4] fp32
    const float* bias = (const float*)d_in[3];   // [512]   fp32
    float* out        = (float*)d_out;

    const int BT = in_sizes[0] / D_INP;               // 3072
    const int S  = out_size / (BT * D_MODEL);         // 64
    const size_t N4 = (size_t)out_size / 4;           // 25,165,824 float4

    const int GRID = 2048;
    const size_t stride = (size_t)GRID * 256;         // 524,288

    // Specialized path hardwires S=64 geometry (btStep=64, shift=13).
    if (S == 64 && N4 % stride == 0 && (N4 / stride) == 48) {
        tfe_sload<48><<<GRID, 256, 0, stream>>>(
            (const float4*)x, (const float4*)W, (const float4*)bias,
            (float4*)out);
    } else {
        tfe_flat<<<GRID, 256, 0, stream>>>(
            (const float4*)x, (const float4*)W, (const float4*)bias,
            (float4*)out, N4, S * (D_MODEL / 4));
    }
}

// Round 7
// 407.793 us; speedup vs baseline: 1.1652x; 1.1652x over previous
//
#include <hip/hip_runtime.h>
#include <hip/hip_bf16.h>

// TimeFeatureEmbedding: y[b,t,d] = sum_e x[b,t,e]*W[d,e] + b[d], broadcast to
// [B,T,S,D]. D=512, d_inp=4, S=64. 402.7 MB fp32 stores -> write-BW-bound.
//
// Scoreboard (kernel-only = total minus ~320us harness fills):
//   R1 block-per-bt 137us | R2 flat+vmem-load 84us (4.8 TB/s) | R3 reg-
//   precompute 91us (occupancy loss) | R5 nt 110us (loses L2 write-combining)
//   | R6 s_load 156us (SGPR-serialized scalar loads).
// This round: stage the block's 48 x rows in LDS once (768B), then the store
// loop reads x via ds_read_b128 (lgkmcnt) -> zero vmem loads in the loop, so
// stores never wait behind a load's vmcnt; full 8 blocks/CU occupancy.

#define D_MODEL 512
#define D_INP   4

template<int ITERS>
__global__ __launch_bounds__(256, 8) void tfe_lds(
    const float4* __restrict__ x4,   // [BT]  x rows as float4
    const float4* __restrict__ W4,   // [512] each W row is one float4
    const float4* __restrict__ b4,   // [128] bias as float4
    float4* __restrict__ out4)       // flat output as float4
{
    // Specialized geometry: S=64 -> bt-chunk 8192 float4; grid=2048 ->
    // stride 524288 float4 -> per-block bt_i = (blockIdx>>5) + 64*i.
    __shared__ float4 xs[ITERS];
    const int tid = threadIdx.x;
    const int bt0 = (int)(blockIdx.x >> 5);
    if (tid < ITERS) xs[tid] = x4[bt0 + tid * 64];   // one-time stage

    const size_t stride = (size_t)gridDim.x * 256;   // 524288
    const size_t f0 = (size_t)blockIdx.x * 256 + tid;
    const int d4 = (int)(f0 & 127);

    const float4 w0 = W4[4 * d4 + 0];
    const float4 w1 = W4[4 * d4 + 1];
    const float4 w2 = W4[4 * d4 + 2];
    const float4 w3 = W4[4 * d4 + 3];
    const float4 bv = b4[d4];

    __syncthreads();   // xs ready; after this, NO vmem loads remain

    size_t f = f0;
#pragma unroll
    for (int i = 0; i < ITERS; ++i, f += stride) {
        const float4 xv = xs[i];   // ds_read_b128, same addr all lanes ->
                                   // broadcast, lgkmcnt (not vmcnt)
        float4 y;
        y.x = fmaf(xv.x, w0.x, fmaf(xv.y, w0.y, fmaf(xv.z, w0.z, fmaf(xv.w, w0.w, bv.x))));
        y.y = fmaf(xv.x, w1.x, fmaf(xv.y, w1.y, fmaf(xv.z, w1.z, fmaf(xv.w, w1.w, bv.y))));
        y.z = fmaf(xv.x, w2.x, fmaf(xv.y, w2.y, fmaf(xv.z, w2.z, fmaf(xv.w, w2.w, bv.z))));
        y.w = fmaf(xv.x, w3.x, fmaf(xv.y, w3.y, fmaf(xv.z, w3.z, fmaf(xv.w, w3.w, bv.w))));
        out4[f] = y;   // fire-and-forget; nothing in the loop waits on vmcnt
    }
}

// Generic fallback (any S / sizes): R2's flat grid-stride kernel (best so far).
__global__ __launch_bounds__(256) void tfe_flat(
    const float4* __restrict__ x4, const float4* __restrict__ W4,
    const float4* __restrict__ b4, float4* __restrict__ out4,
    size_t N4, int rowLen /* S*128 */)
{
    const size_t stride = (size_t)gridDim.x * blockDim.x;
    for (size_t f = (size_t)blockIdx.x * blockDim.x + threadIdx.x; f < N4; f += stride) {
        const int d4 = (int)(f & 127);
        const int bt = (int)(f / (size_t)rowLen);
        const float4 xv = x4[bt];
        const float4 w0 = W4[4 * d4 + 0];
        const float4 w1 = W4[4 * d4 + 1];
        const float4 w2 = W4[4 * d4 + 2];
        const float4 w3 = W4[4 * d4 + 3];
        const float4 bv = b4[d4];
        float4 y;
        y.x = fmaf(xv.x, w0.x, fmaf(xv.y, w0.y, fmaf(xv.z, w0.z, fmaf(xv.w, w0.w, bv.x))));
        y.y = fmaf(xv.x, w1.x, fmaf(xv.y, w1.y, fmaf(xv.z, w1.z, fmaf(xv.w, w1.w, bv.y))));
        y.z = fmaf(xv.x, w2.x, fmaf(xv.y, w2.y, fmaf(xv.z, w2.z, fmaf(xv.w, w2.w, bv.z))));
        y.w = fmaf(xv.x, w3.x, fmaf(xv.y, w3.y, fmaf(xv.z, w3.z, fmaf(xv.w, w3.w, bv.w))));
        out4[f] = y;
    }
}

extern "C" void kernel_launch(void* const* d_in, const int* in_sizes, int n_in,
                              void* d_out, int out_size, void* d_ws, size_t ws_size,
                              hipStream_t stream) {
    const float* x    = (const float*)d_in[0];   // [B,T,4] fp32
    const float* W    = (const float*)d_in[2];   // [512,4] fp32
    const float* bias = (const float*)d_in[3];   // [512]   fp32
    float* out        = (float*)d_out;

    const int BT = in_sizes[0] / D_INP;               // 3072
    const int S  = out_size / (BT * D_MODEL);         // 64
    const size_t N4 = (size_t)out_size / 4;           // 25,165,824 float4

    const int GRID = 2048;
    const size_t stride = (size_t)GRID * 256;         // 524,288

    if (S == 64 && N4 % stride == 0 && (N4 / stride) == 48) {
        tfe_lds<48><<<GRID, 256, 0, stream>>>(
            (const float4*)x, (const float4*)W, (const float4*)bias,
            (float4*)out);
    } else {
        tfe_flat<<<GRID, 256, 0, stream>>>(
            (const float4*)x, (const float4*)W, (const float4*)bias,
            (float4*)out, N4, S * (D_MODEL / 4));
    }
}